// Round 4
// baseline (470.927 us; speedup 1.0000x reference)
//
#include <hip/hip_runtime.h>
#include <hip/hip_bf16.h>

// ---------------------------------------------------------------------------
// Positional-encoding table PE[s][d], fp32 (1024 x 512)
// ---------------------------------------------------------------------------
__global__ __launch_bounds__(256) void pe_k(float* __restrict__ PE)
{
    int idx = blockIdx.x * 256 + threadIdx.x;      // < 524288
    int d = idx & 511, s = idx >> 9;
    float expo = (float)(d & ~1) * (1.0f / 512.0f);
    float ang = (float)s * exp2f(-expo * 13.287712379549449f); // 10000^-expo
    PE[idx] = (d & 1) ? cosf(ang) : sinf(ang);
}

// ---------------------------------------------------------------------------
// zero fill (w + gamma)
// ---------------------------------------------------------------------------
__global__ __launch_bounds__(256) void zero_k(float4* __restrict__ p, int n4)
{
    int i = blockIdx.x * 256 + threadIdx.x;
    if (i < n4) p[i] = make_float4(0.f, 0.f, 0.f, 0.f);
}

// ---------------------------------------------------------------------------
// qr_k: per (b,h): X0row = emb[tok[b,0]] + PE[0];
//   q0[f] = X0row . Wq[h][:,f] + bq[f]
//   alpha[b,h] = q0 . bk[h]
//   rT[d][b*4+h] = sum_f q0[f] * Wk[h][d][f]
// Grid (32 b, 4 h).
// ---------------------------------------------------------------------------
__global__ __launch_bounds__(256) void qr_k(
    const int* __restrict__ inp, const float* __restrict__ emb,
    const float* __restrict__ PE, const float* __restrict__ Wp,
    const float* __restrict__ bp, float* __restrict__ X0,
    float* __restrict__ rT, float* __restrict__ alpha)
{
    __shared__ float xs[512];
    __shared__ float red[256];
    __shared__ float q0s[128];
    int b = blockIdx.x, h = blockIdx.y, t = threadIdx.x;
    int tok0 = inp[b * 1024];
#pragma unroll
    for (int rep = 0; rep < 2; rep++) {
        int d = t + rep * 256;
        float v = emb[(long)tok0 * 512 + d] + PE[d];
        xs[d] = v;
        if (h == 0) X0[b * 512 + d] = v;
    }
    __syncthreads();

    int f = t & 127, dh = t >> 7;
    const float* wq = Wp + (long)h * 196608 + f;
    float acc = 0.f;
#pragma unroll 8
    for (int d = dh * 256; d < dh * 256 + 256; d++)
        acc += xs[d] * wq[(long)d * 384];
    red[t] = acc;
    __syncthreads();
    if (t < 128) q0s[t] = red[t] + red[t + 128] + bp[h * 384 + t];
    __syncthreads();
    if (t < 128) red[t] = q0s[t] * bp[h * 384 + 128 + t];
    __syncthreads();
    for (int w = 64; w >= 1; w >>= 1) {
        if (t < w) red[t] += red[t + w];
        __syncthreads();
    }
    if (t == 0) alpha[b * 4 + h] = red[0];

    const float4* q4 = (const float4*)q0s;
#pragma unroll
    for (int rep = 0; rep < 2; rep++) {
        int d = t + rep * 256;
        const float4* wr = (const float4*)(Wp + ((long)(h * 512 + d)) * 384 + 128);
        float a2 = 0.f;
#pragma unroll 8
        for (int f4 = 0; f4 < 32; f4++) {
            float4 w = wr[f4], qq = q4[f4];
            a2 += w.x * qq.x + w.y * qq.y + w.z * qq.z + w.w * qq.w;
        }
        rT[d * 128 + b * 4 + h] = a2;
    }
}

// ---------------------------------------------------------------------------
// er_k: ERP[row][bh] for row<8192: emb[row] @ rT (guard row<8185);
//       row in [8192,9216): PE[row-8192] @ rT.
// GEMM M=9216, N=128, K=512. Grid (bn=2, bm=144). BM=64,BN=64,BK=16.
// ---------------------------------------------------------------------------
__global__ __launch_bounds__(256) void er_k(
    const float* __restrict__ emb, const float* __restrict__ PE,
    const float* __restrict__ rT, float* __restrict__ ERP)
{
    __shared__ float As[16][65];
    __shared__ float Bs[16][65];
    int bm = blockIdx.y, bn = blockIdx.x, t = threadIdx.x;
    int row0 = bm * 64;
    const float* A; int rowbase, Mlim;
    if (row0 < 8192) { A = emb; rowbase = row0; Mlim = 8185; }
    else             { A = PE;  rowbase = row0 - 8192; Mlim = 1024; }

    int tm = (t >> 4) << 2, tn = (t & 15) << 2;
    float acc[4][4] = {};
    for (int k0 = 0; k0 < 512; k0 += 16) {
#pragma unroll
        for (int tt = 0; tt < 4; tt++) {
            int i = t + tt * 256;
            int m = i >> 4, kk = i & 15;
            int gm = rowbase + m;
            As[kk][m] = (gm < Mlim) ? A[(long)gm * 512 + k0 + kk] : 0.f;
            int n = i & 63, kk2 = i >> 6;
            Bs[kk2][n] = rT[(k0 + kk2) * 128 + bn * 64 + n];
        }
        __syncthreads();
#pragma unroll
        for (int kk = 0; kk < 16; kk++) {
            float a[4], bb[4];
#pragma unroll
            for (int i = 0; i < 4; i++) a[i] = As[kk][tm + i];
#pragma unroll
            for (int j = 0; j < 4; j++) bb[j] = Bs[kk][tn + j];
#pragma unroll
            for (int i = 0; i < 4; i++)
#pragma unroll
                for (int j = 0; j < 4; j++) acc[i][j] += a[i] * bb[j];
        }
        __syncthreads();
    }
#pragma unroll
    for (int i = 0; i < 4; i++)
#pragma unroll
        for (int j = 0; j < 4; j++)
            ERP[(long)(row0 + tm + i) * 128 + bn * 64 + tn + j] = acc[i][j];
}

// ---------------------------------------------------------------------------
// u_k: u = ER[tok] + PEr[s] + alpha (float4 over h);
//   U[s][b*4+h] = u;  w[tok][b*4+h] += u (atomic);  gamma[b*4+h] += sum_s u.
// Grid (32 b, 4 sc), lane = s within 256-chunk.
// ---------------------------------------------------------------------------
__global__ __launch_bounds__(256) void u_k(
    const int* __restrict__ inp, const float* __restrict__ ERP,
    const float* __restrict__ alpha, float* __restrict__ U,
    float* __restrict__ w, float* __restrict__ gamma)
{
    __shared__ float gred[4][4];
    int b = blockIdx.x, sc = blockIdx.y, t = threadIdx.x;
    int s = sc * 256 + t;
    int tok = inp[b * 1024 + s];
    float4 er = *(const float4*)&ERP[(long)tok * 128 + b * 4];
    float4 pr = *(const float4*)&ERP[(long)(8192 + s) * 128 + b * 4];
    float4 al = *(const float4*)&alpha[b * 4];
    float4 uv = make_float4(er.x + pr.x + al.x, er.y + pr.y + al.y,
                            er.z + pr.z + al.z, er.w + pr.w + al.w);
    *(float4*)&U[s * 128 + b * 4] = uv;
    atomicAdd(&w[(long)tok * 128 + b * 4 + 0], uv.x);
    atomicAdd(&w[(long)tok * 128 + b * 4 + 1], uv.y);
    atomicAdd(&w[(long)tok * 128 + b * 4 + 2], uv.z);
    atomicAdd(&w[(long)tok * 128 + b * 4 + 3], uv.w);

    float4 p = uv;
#pragma unroll
    for (int off = 32; off; off >>= 1) {
        p.x += __shfl_down(p.x, off);
        p.y += __shfl_down(p.y, off);
        p.z += __shfl_down(p.z, off);
        p.w += __shfl_down(p.w, off);
    }
    if ((t & 63) == 0) {
        int wv = t >> 6;
        gred[wv][0] = p.x; gred[wv][1] = p.y; gred[wv][2] = p.z; gred[wv][3] = p.w;
    }
    __syncthreads();
    if (t < 4) {
        float v = gred[0][t] + gred[1][t] + gred[2][t] + gred[3][t];
        atomicAdd(&gamma[b * 4 + t], v);
    }
}

// ---------------------------------------------------------------------------
// tw_k: split-K GEMM. Tpp[kz][d][bh]:
//   kz<16 : chunk of emb^T @ w  (k = vocab rows, guard k<8185)
//   kz>=16: chunk of PE^T @ U   (k = s rows)
// C[m=d<512][n=bh<128]. Grid (bn=2, bm=8, kz=18). BM=64,BN=64,BK=32.
// A[k][m] (TA layout, coalesced along m), B[k][n].
// ---------------------------------------------------------------------------
__global__ __launch_bounds__(256) void tw_k(
    const float* __restrict__ emb, const float* __restrict__ PE,
    const float* __restrict__ w, const float* __restrict__ U,
    float* __restrict__ Tpp)
{
    __shared__ float As[32][65];
    __shared__ float Bs[32][65];
    int bn = blockIdx.x, bm = blockIdx.y, kz = blockIdx.z, t = threadIdx.x;
    const float* A; const float* Bsrc; int koff, kguard;
    if (kz < 16) { A = emb; Bsrc = w; koff = kz * 512; kguard = 8185; }
    else         { A = PE;  Bsrc = U; koff = (kz - 16) * 512; kguard = 1 << 30; }

    int tm = (t >> 4) << 2, tn = (t & 15) << 2;
    float acc[4][4] = {};
    for (int kk0 = 0; kk0 < 512; kk0 += 32) {
#pragma unroll
        for (int tt = 0; tt < 8; tt++) {
            int i = t + tt * 256;          // 0..2047
            int m = i & 63, kk = i >> 6;   // kk 0..31
            int gk = koff + kk0 + kk;
            bool ok = gk < kguard;
            As[kk][m] = ok ? A[(long)gk * 512 + bm * 64 + m] : 0.f;
            Bs[kk][m] = ok ? Bsrc[(long)gk * 128 + bn * 64 + m] : 0.f;
        }
        __syncthreads();
#pragma unroll
        for (int kk = 0; kk < 32; kk++) {
            float a[4], bb[4];
#pragma unroll
            for (int i = 0; i < 4; i++) a[i] = As[kk][tm + i];
#pragma unroll
            for (int j = 0; j < 4; j++) bb[j] = Bs[kk][tn + j];
#pragma unroll
            for (int i = 0; i < 4; i++)
#pragma unroll
                for (int j = 0; j < 4; j++) acc[i][j] += a[i] * bb[j];
        }
        __syncthreads();
    }
#pragma unroll
    for (int i = 0; i < 4; i++)
#pragma unroll
        for (int j = 0; j < 4; j++)
            Tpp[(long)kz * 65536 + (long)(bm * 64 + tm + i) * 128 + bn * 64 + tn + j]
                = acc[i][j];
}

// ---------------------------------------------------------------------------
// att_k: per b: t'[h][d] = sum_kz Tpp;  c0 = scale*(t' @ Wv + gamma*bv);
//   attn = c0 @ Wo + bo;  Y1 = LN(attn + X0).   Grid 32.
// ---------------------------------------------------------------------------
__global__ __launch_bounds__(256) void att_k(
    const float* __restrict__ Tpp, const float* __restrict__ gamma,
    const float* __restrict__ Wp, const float* __restrict__ bp,
    const float* __restrict__ Wo, const float* __restrict__ bo,
    const float* __restrict__ X0, const float* __restrict__ g1,
    const float* __restrict__ b1v, float* __restrict__ Y1)
{
    __shared__ float tp[2048];     // [h][512]
    __shared__ float c0s[512];
    __shared__ float sd[8];
    int b = blockIdx.x, t = threadIdx.x;

    float4 t0 = make_float4(0, 0, 0, 0), t1 = make_float4(0, 0, 0, 0);
#pragma unroll
    for (int kz = 0; kz < 18; kz++) {
        float4 v0 = *(const float4*)&Tpp[(long)kz * 65536 + (long)t * 128 + b * 4];
        float4 v1 = *(const float4*)&Tpp[(long)kz * 65536 + (long)(t + 256) * 128 + b * 4];
        t0.x += v0.x; t0.y += v0.y; t0.z += v0.z; t0.w += v0.w;
        t1.x += v1.x; t1.y += v1.y; t1.z += v1.z; t1.w += v1.w;
    }
    tp[t] = t0.x; tp[512 + t] = t0.y; tp[1024 + t] = t0.z; tp[1536 + t] = t0.w;
    tp[t + 256] = t1.x; tp[512 + t + 256] = t1.y;
    tp[1024 + t + 256] = t1.z; tp[1536 + t + 256] = t1.w;
    __syncthreads();

#pragma unroll
    for (int rep = 0; rep < 2; rep++) {
        int j = t + rep * 256;
        int h = j >> 7, e = j & 127;
        const float* wv = Wp + (long)h * 196608 + 256 + e;
        const float* tph = &tp[h * 512];
        float acc = 0.f;
#pragma unroll 8
        for (int d = 0; d < 512; d++) acc += tph[d] * wv[(long)d * 384];
        c0s[j] = 0.03125f * (acc + gamma[b * 4 + h] * bp[h * 384 + 256 + e]);
    }
    __syncthreads();

    float a01[2];
#pragma unroll
    for (int rep = 0; rep < 2; rep++) {
        int j = t + rep * 256;
        float acc = bo[j];
#pragma unroll 8
        for (int d = 0; d < 512; d++) acc += c0s[d] * Wo[(long)d * 512 + j];
        a01[rep] = acc + X0[b * 512 + j];
    }
    float a0 = a01[0], a1 = a01[1];
    float s = a0 + a1;
#pragma unroll
    for (int off = 32; off; off >>= 1) s += __shfl_down(s, off);
    if ((t & 63) == 0) sd[t >> 6] = s;
    __syncthreads();
    float mean = (sd[0] + sd[1] + sd[2] + sd[3]) * (1.0f / 512.0f);
    float d0 = a0 - mean, d1 = a1 - mean;
    float v = d0 * d0 + d1 * d1;
#pragma unroll
    for (int off = 32; off; off >>= 1) v += __shfl_down(v, off);
    if ((t & 63) == 0) sd[4 + (t >> 6)] = v;
    __syncthreads();
    float var = (sd[4] + sd[5] + sd[6] + sd[7]) * (1.0f / 512.0f);
    float rstd = rsqrtf(var + 0.001f);
    Y1[b * 512 + t] = d0 * rstd * g1[t] + b1v[t];
    Y1[b * 512 + t + 256] = d1 * rstd * g1[t + 256] + b1v[t + 256];
}

// ---------------------------------------------------------------------------
// FFN1 partials: Hp1[ks][32][2048] = Y1[:, kchunk] @ W1[kchunk, :]
// Grid (32 jt, 4 ks).
// ---------------------------------------------------------------------------
__global__ __launch_bounds__(256) void ffn1_k(
    const float* __restrict__ Y1, const float* __restrict__ W1,
    float* __restrict__ Hp1)
{
    __shared__ float at[32][128];
    int jt = blockIdx.x, ks = blockIdx.y, t = threadIdx.x;
#pragma unroll
    for (int i = 0; i < 4; i++) {
        int idx = t + i * 256;
        int row = idx >> 5, f4 = idx & 31;
        ((float4*)at)[idx] = ((const float4*)(Y1 + (long)row * 512 + ks * 128))[f4];
    }
    __syncthreads();
    int j = jt * 64 + (t & 63), rg = t >> 6;
    float acc[8] = {};
    const float* wp = W1 + (long)(ks * 128) * 2048 + j;
#pragma unroll 4
    for (int k = 0; k < 128; k++) {
        float wv = wp[(long)k * 2048];
#pragma unroll
        for (int rr = 0; rr < 8; rr++)
            acc[rr] += at[rg * 8 + rr][k] * wv;
    }
#pragma unroll
    for (int rr = 0; rr < 8; rr++)
        Hp1[((long)(ks * 32 + rg * 8 + rr)) * 2048 + j] = acc[rr];
}

// ---------------------------------------------------------------------------
// FFN2 partials, with fused H1 = relu(sum_ks Hp1 + b1) at staging.
// Hp2[ks][32][512] = H1[:, kchunk] @ W2[kchunk, :].  Grid (8 jt, 16 ks).
// ---------------------------------------------------------------------------
__global__ __launch_bounds__(256) void ffn2_k(
    const float* __restrict__ Hp1, const float* __restrict__ b1,
    const float* __restrict__ W2, float* __restrict__ Hp2)
{
    __shared__ float at[32][128];
    int jt = blockIdx.x, ks = blockIdx.y, t = threadIdx.x;
#pragma unroll
    for (int i = 0; i < 4; i++) {
        int idx = t + i * 256;
        int row = idx >> 5, f4 = idx & 31;
        int col4 = ks * 32 + f4;
        float4 v = ((const float4*)b1)[col4];
#pragma unroll
        for (int p = 0; p < 4; p++) {
            float4 pv = ((const float4*)Hp1)[(long)p * 16384 + (long)row * 512 + col4];
            v.x += pv.x; v.y += pv.y; v.z += pv.z; v.w += pv.w;
        }
        v.x = fmaxf(v.x, 0.f); v.y = fmaxf(v.y, 0.f);
        v.z = fmaxf(v.z, 0.f); v.w = fmaxf(v.w, 0.f);
        ((float4*)at)[idx] = v;
    }
    __syncthreads();
    int j = jt * 64 + (t & 63), rg = t >> 6;
    float acc[8] = {};
    const float* wp = W2 + (long)(ks * 128) * 512 + j;
#pragma unroll 4
    for (int k = 0; k < 128; k++) {
        float wv = wp[(long)k * 512];
#pragma unroll
        for (int rr = 0; rr < 8; rr++)
            acc[rr] += at[rg * 8 + rr][k] * wv;
    }
#pragma unroll
    for (int rr = 0; rr < 8; rr++)
        Hp2[((long)(ks * 32 + rg * 8 + rr)) * 512 + j] = acc[rr];
}

// ---------------------------------------------------------------------------
// tail_k: X2 = LN(sum Hp2 + b2 + Y1); hid = relu(X2@Wh+bh);
//   logit = hid@Wf+bf; out = [logit, sigmoid].  Grid 32.
// ---------------------------------------------------------------------------
__global__ __launch_bounds__(256) void tail_k(
    const float* __restrict__ Hp2, const float* __restrict__ b2,
    const float* __restrict__ Y1, const float* __restrict__ g,
    const float* __restrict__ bta, const float* __restrict__ Wh,
    const float* __restrict__ bh, const float* __restrict__ Wf,
    const float* __restrict__ bf, float* __restrict__ out)
{
    __shared__ float sd[8];
    __shared__ float xs[512];
    int b = blockIdx.x, t = threadIdx.x;
    float a[2];
#pragma unroll
    for (int rep = 0; rep < 2; rep++) {
        int j = t + rep * 256;
        float v = b2[j] + Y1[b * 512 + j];
#pragma unroll
        for (int ks = 0; ks < 16; ks++)
            v += Hp2[((long)(ks * 32 + b)) * 512 + j];
        a[rep] = v;
    }
    float s = a[0] + a[1];
#pragma unroll
    for (int off = 32; off; off >>= 1) s += __shfl_down(s, off);
    if ((t & 63) == 0) sd[t >> 6] = s;
    __syncthreads();
    float mean = (sd[0] + sd[1] + sd[2] + sd[3]) * (1.0f / 512.0f);
    float d0 = a[0] - mean, d1 = a[1] - mean;
    float v2 = d0 * d0 + d1 * d1;
#pragma unroll
    for (int off = 32; off; off >>= 1) v2 += __shfl_down(v2, off);
    if ((t & 63) == 0) sd[4 + (t >> 6)] = v2;
    __syncthreads();
    float var = (sd[4] + sd[5] + sd[6] + sd[7]) * (1.0f / 512.0f);
    float rstd = rsqrtf(var + 0.001f);
    xs[t] = d0 * rstd * g[t] + bta[t];
    xs[t + 256] = d1 * rstd * g[t + 256] + bta[t + 256];
    __syncthreads();

    float p = 0.f;
#pragma unroll
    for (int rep = 0; rep < 2; rep++) {
        int j = t + rep * 256;
        float acc = bh[j];
#pragma unroll 8
        for (int d = 0; d < 512; d++) acc += xs[d] * Wh[(long)d * 512 + j];
        p += fmaxf(acc, 0.f) * Wf[j];
    }
#pragma unroll
    for (int off = 32; off; off >>= 1) p += __shfl_down(p, off);
    if ((t & 63) == 0) sd[t >> 6] = p;
    __syncthreads();
    if (t == 0) {
        float logit = sd[0] + sd[1] + sd[2] + sd[3] + bf[0];
        out[b] = logit;
        out[32 + b] = 1.f / (1.f + expf(-logit));
    }
}

// ---------------------------------------------------------------------------
extern "C" void kernel_launch(void* const* d_in, const int* in_sizes, int n_in,
                              void* d_out, int out_size, void* d_ws, size_t ws_size,
                              hipStream_t stream)
{
    const int*   inputs = (const int*)  d_in[0];
    const float* emb    = (const float*)d_in[1];
    const float* Wp     = (const float*)d_in[2];
    const float* bp     = (const float*)d_in[3];
    const float* Wo     = (const float*)d_in[4];
    const float* bo     = (const float*)d_in[5];
    const float* ln1_g  = (const float*)d_in[6];
    const float* ln1_b  = (const float*)d_in[7];
    const float* W1     = (const float*)d_in[8];
    const float* b1     = (const float*)d_in[9];
    const float* W2     = (const float*)d_in[10];
    const float* b2     = (const float*)d_in[11];
    const float* ln2_g  = (const float*)d_in[12];
    const float* ln2_b  = (const float*)d_in[13];
    const float* Wh     = (const float*)d_in[14];
    const float* bh     = (const float*)d_in[15];
    const float* Wf     = (const float*)d_in[16];
    const float* bf     = (const float*)d_in[17];
    float* out = (float*)d_out;

    char* p = (char*)d_ws;
    float* PE    = (float*)p;  p += 2097152;    // (1024,512)
    float* X0    = (float*)p;  p += 65536;      // (32,512)
    float* rT    = (float*)p;  p += 262144;     // (512,128)
    float* alpha = (float*)p;  p += 1024;       // (128) +pad
    float* ERP   = (float*)p;  p += 4718592;    // (9216,128)
    float* w     = (float*)p;  p += 4194304;    // (8192,128)  [zeroed]
    float* gamma = (float*)p;  p += 1024;       // (128)       [zeroed, adjacent]
    float* U     = (float*)p;  p += 524288;     // (1024,128)
    float* Tpp   = (float*)p;  p += 4718592;    // (18,512,128)
    float* Y1    = (float*)p;  p += 65536;      // (32,512)
    float* Hp1   = (float*)p;  p += 1048576;    // (4,32,2048)
    float* Hp2   = (float*)p;  p += 1048576;    // (16,32,512)

    int zero_n4 = (4194304 + 1024) / 16;        // w + gamma region
    pe_k<<<2048, 256, 0, stream>>>(PE);
    zero_k<<<(zero_n4 + 255) / 256, 256, 0, stream>>>((float4*)w, zero_n4);
    qr_k<<<dim3(32, 4), 256, 0, stream>>>(inputs, emb, PE, Wp, bp, X0, rT, alpha);
    er_k<<<dim3(2, 144), 256, 0, stream>>>(emb, PE, rT, ERP);
    u_k<<<dim3(32, 4), 256, 0, stream>>>(inputs, ERP, alpha, U, w, gamma);
    tw_k<<<dim3(2, 8, 18), 256, 0, stream>>>(emb, PE, w, U, Tpp);
    att_k<<<32, 256, 0, stream>>>(Tpp, gamma, Wp, bp, Wo, bo, X0, ln1_g, ln1_b, Y1);
    ffn1_k<<<dim3(32, 4), 256, 0, stream>>>(Y1, W1, Hp1);
    ffn2_k<<<dim3(8, 16), 256, 0, stream>>>(Hp1, b1, W2, Hp2);
    tail_k<<<32, 256, 0, stream>>>(Hp2, b2, Y1, ln2_g, ln2_b, Wh, bh, Wf, bf, out);
}

// Round 5
// 244.777 us; speedup vs baseline: 1.9239x; 1.9239x over previous
//
#include <hip/hip_runtime.h>
#include <hip/hip_bf16.h>

// ---------------------------------------------------------------------------
// Positional-encoding table PE[s][d], fp32 (1024 x 512)
// ---------------------------------------------------------------------------
__global__ __launch_bounds__(256) void pe_k(float* __restrict__ PE)
{
    int idx = blockIdx.x * 256 + threadIdx.x;      // < 524288
    int d = idx & 511, s = idx >> 9;
    float expo = (float)(d & ~1) * (1.0f / 512.0f);
    float ang = (float)s * exp2f(-expo * 13.287712379549449f); // 10000^-expo
    PE[idx] = (d & 1) ? cosf(ang) : sinf(ang);
}

// ---------------------------------------------------------------------------
// zero gamma (128 floats)
// ---------------------------------------------------------------------------
__global__ __launch_bounds__(128) void zero_k(float* __restrict__ p)
{
    p[threadIdx.x] = 0.f;
}

// ---------------------------------------------------------------------------
// qr_k: per (b,h): X0row = emb[tok[b,0]] + PE[0];
//   q0[f] = X0row . Wq[h][:,f] + bq[f];  alpha[b,h] = q0 . bk[h]
//   r[(b*4+h)][d] = sum_f q0[f] * Wk[h][d][f]
// Grid (32 b, 4 h).
// ---------------------------------------------------------------------------
__global__ __launch_bounds__(256) void qr_k(
    const int* __restrict__ inp, const float* __restrict__ emb,
    const float* __restrict__ PE, const float* __restrict__ Wp,
    const float* __restrict__ bp, float* __restrict__ X0,
    float* __restrict__ r, float* __restrict__ alpha)
{
    __shared__ float xs[512];
    __shared__ float red[256];
    __shared__ float q0s[128];
    int b = blockIdx.x, h = blockIdx.y, t = threadIdx.x;
    int tok0 = inp[b * 1024];
#pragma unroll
    for (int rep = 0; rep < 2; rep++) {
        int d = t + rep * 256;
        float v = emb[(long)tok0 * 512 + d] + PE[d];
        xs[d] = v;
        if (h == 0) X0[b * 512 + d] = v;
    }
    __syncthreads();

    int f = t & 127, dh = t >> 7;
    const float* wq = Wp + (long)h * 196608 + f;
    float acc = 0.f;
#pragma unroll 8
    for (int d = dh * 256; d < dh * 256 + 256; d++)
        acc += xs[d] * wq[(long)d * 384];
    red[t] = acc;
    __syncthreads();
    if (t < 128) q0s[t] = red[t] + red[t + 128] + bp[h * 384 + t];
    __syncthreads();
    if (t < 128) red[t] = q0s[t] * bp[h * 384 + 128 + t];
    __syncthreads();
    for (int w = 64; w >= 1; w >>= 1) {
        if (t < w) red[t] += red[t + w];
        __syncthreads();
    }
    if (t == 0) alpha[b * 4 + h] = red[0];

    const float4* q4 = (const float4*)q0s;
#pragma unroll
    for (int rep = 0; rep < 2; rep++) {
        int d = t + rep * 256;
        const float4* wr = (const float4*)(Wp + ((long)(h * 512 + d)) * 384 + 128);
        float a2 = 0.f;
#pragma unroll 8
        for (int f4 = 0; f4 < 32; f4++) {
            float4 w = wr[f4], qq = q4[f4];
            a2 += w.x * qq.x + w.y * qq.y + w.z * qq.z + w.w * qq.w;
        }
        r[((long)(b * 4 + h)) * 512 + d] = a2;
    }
}

// ---------------------------------------------------------------------------
// u2_k: u[b,h,s] = (emb[tok]+PE[s]) . r[b,h] + alpha[b,h]
//   U[s][b*4+h] = u;  gamma[b,h] += sum_s u (atomic).
// Grid (32 b, 8 sc); wave-per-s; r held in per-lane registers.
// ---------------------------------------------------------------------------
__global__ __launch_bounds__(256) void u2_k(
    const int* __restrict__ inp, const float* __restrict__ emb,
    const float* __restrict__ PE, const float* __restrict__ r,
    const float* __restrict__ alpha, float* __restrict__ U,
    float* __restrict__ gamma)
{
    __shared__ float gred[4][4];
    int b = blockIdx.x, sc = blockIdx.y, t = threadIdx.x;
    int wave = t >> 6, lane = t & 63;

    float4 ra[4][2];
    float al[4];
#pragma unroll
    for (int h = 0; h < 4; h++) {
        ra[h][0] = *(const float4*)&r[((long)(b * 4 + h)) * 512 + lane * 8];
        ra[h][1] = *(const float4*)&r[((long)(b * 4 + h)) * 512 + lane * 8 + 4];
        al[h] = alpha[b * 4 + h];
    }
    float gacc[4] = {0.f, 0.f, 0.f, 0.f};
    int sbase = sc * 128 + wave * 32;
#pragma unroll 1
    for (int si = 0; si < 32; si++) {
        int s = sbase + si;
        int tok = inp[b * 1024 + s];
        float4 e0 = *(const float4*)&emb[(long)tok * 512 + lane * 8];
        float4 e1 = *(const float4*)&emb[(long)tok * 512 + lane * 8 + 4];
        float4 p0 = *(const float4*)&PE[(long)s * 512 + lane * 8];
        float4 p1 = *(const float4*)&PE[(long)s * 512 + lane * 8 + 4];
        float x0 = e0.x + p0.x, x1 = e0.y + p0.y, x2 = e0.z + p0.z, x3 = e0.w + p0.w;
        float x4 = e1.x + p1.x, x5 = e1.y + p1.y, x6 = e1.z + p1.z, x7 = e1.w + p1.w;
        float acc[4];
#pragma unroll
        for (int h = 0; h < 4; h++) {
            acc[h] = x0 * ra[h][0].x + x1 * ra[h][0].y + x2 * ra[h][0].z + x3 * ra[h][0].w
                   + x4 * ra[h][1].x + x5 * ra[h][1].y + x6 * ra[h][1].z + x7 * ra[h][1].w;
        }
#pragma unroll
        for (int off = 32; off; off >>= 1) {
#pragma unroll
            for (int h = 0; h < 4; h++)
                acc[h] += __shfl_down(acc[h], off);
        }
        if (lane == 0) {
#pragma unroll
            for (int h = 0; h < 4; h++) {
                float uval = acc[h] + al[h];
                U[s * 128 + b * 4 + h] = uval;
                gacc[h] += uval;
            }
        }
    }
    if (lane == 0) {
#pragma unroll
        for (int h = 0; h < 4; h++) gred[wave][h] = gacc[h];
    }
    __syncthreads();
    if (t < 4)
        atomicAdd(&gamma[b * 4 + t],
                  gred[0][t] + gred[1][t] + gred[2][t] + gred[3][t]);
}

// ---------------------------------------------------------------------------
// tp2_k: Tpp[b][sc][h][d] = sum_{s in chunk} (emb[tok,d]+PE[s,d]) * u[b,h,s]
// Grid (32 b, 4 sc). Lanes along d (coalesced float2), u in LDS (broadcast).
// ---------------------------------------------------------------------------
__global__ __launch_bounds__(256) void tp2_k(
    const int* __restrict__ inp, const float* __restrict__ emb,
    const float* __restrict__ PE, const float* __restrict__ U,
    float* __restrict__ Tpp)
{
    __shared__ float uu[4][256];
    int b = blockIdx.x, sc = blockIdx.y, t = threadIdx.x;
    {
        float4 v = *(const float4*)&U[(sc * 256 + t) * 128 + b * 4];
        uu[0][t] = v.x; uu[1][t] = v.y; uu[2][t] = v.z; uu[3][t] = v.w;
    }
    __syncthreads();
    const int* toks = inp + b * 1024 + sc * 256;
    const float* pebase = PE + (long)(sc * 256) * 512 + 2 * t;
    float acc[4][2] = {};
#pragma unroll 4
    for (int sl = 0; sl < 256; sl++) {
        int tok = toks[sl];
        float2 e = *(const float2*)&emb[(long)tok * 512 + 2 * t];
        float2 p = *(const float2*)&pebase[(long)sl * 512];
        float x0 = e.x + p.x, x1 = e.y + p.y;
#pragma unroll
        for (int h = 0; h < 4; h++) {
            float uv = uu[h][sl];
            acc[h][0] += uv * x0;
            acc[h][1] += uv * x1;
        }
    }
#pragma unroll
    for (int h = 0; h < 4; h++)
        *(float2*)&Tpp[((long)((b * 4 + sc) * 4 + h)) * 512 + 2 * t] =
            make_float2(acc[h][0], acc[h][1]);
}

// ---------------------------------------------------------------------------
// att1_k: c0[b, h*128+e] = scale*(sum_d t'[h][d] Wv[h][d][e] + gamma[h] bv[h][e])
// Grid (32 b, 8 jt). Sums the 4 sc-partials of t' on load.
// ---------------------------------------------------------------------------
__global__ __launch_bounds__(256) void att1_k(
    const float* __restrict__ Tpp, const float* __restrict__ gamma,
    const float* __restrict__ Wp, const float* __restrict__ bp,
    float* __restrict__ C0)
{
    __shared__ float tps[512];
    __shared__ float red[256];
    int b = blockIdx.x, jt = blockIdx.y, t = threadIdx.x;
    int h = jt >> 1, e0 = (jt & 1) * 64;
#pragma unroll
    for (int i = 0; i < 2; i++) {
        int d = t + i * 256;
        float v = 0.f;
#pragma unroll
        for (int sc = 0; sc < 4; sc++)
            v += Tpp[((long)((b * 4 + sc) * 4 + h)) * 512 + d];
        tps[d] = v;
    }
    __syncthreads();
    int e = e0 + (t & 63), rg = t >> 6;
    const float* wv = Wp + (long)h * 196608 + 256 + e;
    float acc = 0.f;
#pragma unroll 8
    for (int d = rg * 128; d < rg * 128 + 128; d++)
        acc += tps[d] * wv[(long)d * 384];
    red[t] = acc;
    __syncthreads();
    if (t < 64) {
        float sum = red[t] + red[t + 64] + red[t + 128] + red[t + 192];
        float c = 0.03125f * (sum + gamma[b * 4 + h] * bp[h * 384 + 256 + e0 + t]);
        C0[b * 512 + h * 128 + e0 + t] = c;
    }
}

// ---------------------------------------------------------------------------
// att2_k: ATT0 = c0 @ Wo + bo.  Grid (32 b, 8 jt).
// ---------------------------------------------------------------------------
__global__ __launch_bounds__(256) void att2_k(
    const float* __restrict__ C0, const float* __restrict__ Wo,
    const float* __restrict__ bo, float* __restrict__ ATT0)
{
    __shared__ float c0s[512];
    __shared__ float red[256];
    int b = blockIdx.x, jt = blockIdx.y, t = threadIdx.x;
    c0s[t] = C0[b * 512 + t];
    c0s[t + 256] = C0[b * 512 + t + 256];
    __syncthreads();
    int j = jt * 64 + (t & 63), rg = t >> 6;
    float acc = 0.f;
#pragma unroll 8
    for (int d = rg * 128; d < rg * 128 + 128; d++)
        acc += c0s[d] * Wo[(long)d * 512 + j];
    red[t] = acc;
    __syncthreads();
    if (t < 64) {
        int jj = jt * 64 + t;
        ATT0[b * 512 + jj] = red[t] + red[t + 64] + red[t + 128] + red[t + 192] + bo[jj];
    }
}

// ---------------------------------------------------------------------------
// Row LayerNorm over D=512 with residual:  out = LN(in + res)*g + b
// ---------------------------------------------------------------------------
__global__ __launch_bounds__(256) void ln_rows_k(
    const float* __restrict__ in, const float* __restrict__ res,
    const float* __restrict__ g, const float* __restrict__ bta,
    float* __restrict__ out)
{
    int b = blockIdx.x;
    int t = threadIdx.x;
    float a0 = in[b * 512 + t] + res[b * 512 + t];
    float a1 = in[b * 512 + t + 256] + res[b * 512 + t + 256];

    __shared__ float sd[8];
    float s = a0 + a1;
#pragma unroll
    for (int off = 32; off; off >>= 1) s += __shfl_down(s, off);
    if ((t & 63) == 0) sd[t >> 6] = s;
    __syncthreads();
    float mean = (sd[0] + sd[1] + sd[2] + sd[3]) * (1.0f / 512.0f);

    float d0 = a0 - mean, d1 = a1 - mean;
    float v = d0 * d0 + d1 * d1;
#pragma unroll
    for (int off = 32; off; off >>= 1) v += __shfl_down(v, off);
    if ((t & 63) == 0) sd[4 + (t >> 6)] = v;
    __syncthreads();
    float var = (sd[4] + sd[5] + sd[6] + sd[7]) * (1.0f / 512.0f);
    float rstd = rsqrtf(var + 0.001f);

    out[b * 512 + t] = d0 * rstd * g[t] + bta[t];
    out[b * 512 + t + 256] = d1 * rstd * g[t + 256] + bta[t + 256];
}

// ---------------------------------------------------------------------------
// FFN1 partials: Hp1[ks][32][2048] = Y1[:, kchunk] @ W1[kchunk, :]
// Grid (32 jt, 4 ks).
// ---------------------------------------------------------------------------
__global__ __launch_bounds__(256) void ffn1_k(
    const float* __restrict__ Y1, const float* __restrict__ W1,
    float* __restrict__ Hp1)
{
    __shared__ float at[32][128];
    int jt = blockIdx.x, ks = blockIdx.y, t = threadIdx.x;
#pragma unroll
    for (int i = 0; i < 4; i++) {
        int idx = t + i * 256;
        int row = idx >> 5, f4 = idx & 31;
        ((float4*)at)[idx] = ((const float4*)(Y1 + (long)row * 512 + ks * 128))[f4];
    }
    __syncthreads();
    int j = jt * 64 + (t & 63), rg = t >> 6;
    float acc[8] = {};
    const float* wp = W1 + (long)(ks * 128) * 2048 + j;
#pragma unroll 4
    for (int k = 0; k < 128; k++) {
        float wv = wp[(long)k * 2048];
#pragma unroll
        for (int rr = 0; rr < 8; rr++)
            acc[rr] += at[rg * 8 + rr][k] * wv;
    }
#pragma unroll
    for (int rr = 0; rr < 8; rr++)
        Hp1[((long)(ks * 32 + rg * 8 + rr)) * 2048 + j] = acc[rr];
}

// ---------------------------------------------------------------------------
// FFN2 partials, with fused H1 = relu(sum_ks Hp1 + b1) at staging.
// Hp2[ks][32][512] = H1[:, kchunk] @ W2[kchunk, :].  Grid (8 jt, 16 ks).
// ---------------------------------------------------------------------------
__global__ __launch_bounds__(256) void ffn2_k(
    const float* __restrict__ Hp1, const float* __restrict__ b1,
    const float* __restrict__ W2, float* __restrict__ Hp2)
{
    __shared__ float at[32][128];
    int jt = blockIdx.x, ks = blockIdx.y, t = threadIdx.x;
#pragma unroll
    for (int i = 0; i < 4; i++) {
        int idx = t + i * 256;
        int row = idx >> 5, f4 = idx & 31;
        int col4 = ks * 32 + f4;
        float4 v = ((const float4*)b1)[col4];
#pragma unroll
        for (int p = 0; p < 4; p++) {
            float4 pv = ((const float4*)Hp1)[(long)p * 16384 + (long)row * 512 + col4];
            v.x += pv.x; v.y += pv.y; v.z += pv.z; v.w += pv.w;
        }
        v.x = fmaxf(v.x, 0.f); v.y = fmaxf(v.y, 0.f);
        v.z = fmaxf(v.z, 0.f); v.w = fmaxf(v.w, 0.f);
        ((float4*)at)[idx] = v;
    }
    __syncthreads();
    int j = jt * 64 + (t & 63), rg = t >> 6;
    float acc[8] = {};
    const float* wp = W2 + (long)(ks * 128) * 512 + j;
#pragma unroll 4
    for (int k = 0; k < 128; k++) {
        float wv = wp[(long)k * 512];
#pragma unroll
        for (int rr = 0; rr < 8; rr++)
            acc[rr] += at[rg * 8 + rr][k] * wv;
    }
#pragma unroll
    for (int rr = 0; rr < 8; rr++)
        Hp2[((long)(ks * 32 + rg * 8 + rr)) * 512 + j] = acc[rr];
}

// ---------------------------------------------------------------------------
// X2 = LN(sum_ks Hp2 + b2 + Y1).  Grid 32.
// ---------------------------------------------------------------------------
__global__ __launch_bounds__(256) void ln2_k(
    const float* __restrict__ Hp2, const float* __restrict__ b2,
    const float* __restrict__ Y1, const float* __restrict__ g,
    const float* __restrict__ bta, float* __restrict__ X2)
{
    __shared__ float sd[8];
    int b = blockIdx.x, t = threadIdx.x;
    float a[2];
#pragma unroll
    for (int rep = 0; rep < 2; rep++) {
        int j = t + rep * 256;
        float v = b2[j] + Y1[b * 512 + j];
#pragma unroll
        for (int ks = 0; ks < 16; ks++)
            v += Hp2[((long)(ks * 32 + b)) * 512 + j];
        a[rep] = v;
    }
    float s = a[0] + a[1];
#pragma unroll
    for (int off = 32; off; off >>= 1) s += __shfl_down(s, off);
    if ((t & 63) == 0) sd[t >> 6] = s;
    __syncthreads();
    float mean = (sd[0] + sd[1] + sd[2] + sd[3]) * (1.0f / 512.0f);
    float d0 = a[0] - mean, d1 = a[1] - mean;
    float v2 = d0 * d0 + d1 * d1;
#pragma unroll
    for (int off = 32; off; off >>= 1) v2 += __shfl_down(v2, off);
    if ((t & 63) == 0) sd[4 + (t >> 6)] = v2;
    __syncthreads();
    float var = (sd[4] + sd[5] + sd[6] + sd[7]) * (1.0f / 512.0f);
    float rstd = rsqrtf(var + 0.001f);
    X2[b * 512 + t] = d0 * rstd * g[t] + bta[t];
    X2[b * 512 + t + 256] = d1 * rstd * g[t + 256] + bta[t + 256];
}

// ---------------------------------------------------------------------------
// Head partials: Pl[b][jt] = sum_{j in tile} relu(X2[b].Wh[:,j]+bh[j])*Wf[j]
// Grid (32 b, 8 jt).
// ---------------------------------------------------------------------------
__global__ __launch_bounds__(256) void headp_k(
    const float* __restrict__ X2, const float* __restrict__ Wh,
    const float* __restrict__ bh, const float* __restrict__ Wf,
    float* __restrict__ Pl)
{
    __shared__ float xs[512];
    __shared__ float red[256];
    int b = blockIdx.x, jt = blockIdx.y, t = threadIdx.x;
    xs[t] = X2[b * 512 + t];
    xs[t + 256] = X2[b * 512 + t + 256];
    __syncthreads();
    int j = jt * 64 + (t & 63), rg = t >> 6;
    const float* w = Wh + j;
    float acc = 0.f;
#pragma unroll 8
    for (int d = rg * 128; d < rg * 128 + 128; d++)
        acc += xs[d] * w[(long)d * 512];
    red[t] = acc;
    __syncthreads();
    if (t < 64) {
        int jj = jt * 64 + t;
        float hid = red[t] + red[t + 64] + red[t + 128] + red[t + 192] + bh[jj];
        hid = fmaxf(hid, 0.f);
        float p = hid * Wf[jj];
#pragma unroll
        for (int off = 32; off; off >>= 1) p += __shfl_down(p, off);
        if (t == 0) Pl[b * 8 + jt] = p;
    }
}

__global__ __launch_bounds__(64) void final_k(
    const float* __restrict__ Pl, const float* __restrict__ bf,
    float* __restrict__ out)
{
    int t = threadIdx.x;
    if (t < 32) {
        float logit = bf[0];
#pragma unroll
        for (int jt = 0; jt < 8; jt++) logit += Pl[t * 8 + jt];
        out[t] = logit;
        out[32 + t] = 1.f / (1.f + expf(-logit));
    }
}

// ---------------------------------------------------------------------------
extern "C" void kernel_launch(void* const* d_in, const int* in_sizes, int n_in,
                              void* d_out, int out_size, void* d_ws, size_t ws_size,
                              hipStream_t stream)
{
    const int*   inputs = (const int*)  d_in[0];
    const float* emb    = (const float*)d_in[1];
    const float* Wp     = (const float*)d_in[2];
    const float* bp     = (const float*)d_in[3];
    const float* Wo     = (const float*)d_in[4];
    const float* bo     = (const float*)d_in[5];
    const float* ln1_g  = (const float*)d_in[6];
    const float* ln1_b  = (const float*)d_in[7];
    const float* W1     = (const float*)d_in[8];
    const float* b1     = (const float*)d_in[9];
    const float* W2     = (const float*)d_in[10];
    const float* b2     = (const float*)d_in[11];
    const float* ln2_g  = (const float*)d_in[12];
    const float* ln2_b  = (const float*)d_in[13];
    const float* Wh     = (const float*)d_in[14];
    const float* bh     = (const float*)d_in[15];
    const float* Wf     = (const float*)d_in[16];
    const float* bf     = (const float*)d_in[17];
    float* out = (float*)d_out;

    char* p = (char*)d_ws;
    float* PE    = (float*)p;  p += 2097152;    // (1024,512)
    float* X0    = (float*)p;  p += 65536;      // (32,512)
    float* r     = (float*)p;  p += 262144;     // (128,512)
    float* alpha = (float*)p;  p += 1024;       // (128) +pad
    float* gamma = (float*)p;  p += 1024;       // (128) [zeroed]
    float* U     = (float*)p;  p += 524288;     // (1024,128)
    float* Tpp   = (float*)p;  p += 1048576;    // (32,4,4,512)
    float* C0    = (float*)p;  p += 65536;      // (32,512)
    float* ATT0  = (float*)p;  p += 65536;      // (32,512)
    float* Y1    = (float*)p;  p += 65536;      // (32,512)
    float* Hp1   = (float*)p;  p += 1048576;    // (4,32,2048)
    float* Hp2   = (float*)p;  p += 1048576;    // (16,32,512)
    float* X2    = (float*)p;  p += 65536;      // (32,512)
    float* Pl    = (float*)p;  p += 1024;       // (32,8)

    pe_k<<<2048, 256, 0, stream>>>(PE);
    zero_k<<<1, 128, 0, stream>>>(gamma);
    qr_k<<<dim3(32, 4), 256, 0, stream>>>(inputs, emb, PE, Wp, bp, X0, r, alpha);
    u2_k<<<dim3(32, 8), 256, 0, stream>>>(inputs, emb, PE, r, alpha, U, gamma);
    tp2_k<<<dim3(32, 4), 256, 0, stream>>>(inputs, emb, PE, U, Tpp);
    att1_k<<<dim3(32, 8), 256, 0, stream>>>(Tpp, gamma, Wp, bp, C0);
    att2_k<<<dim3(32, 8), 256, 0, stream>>>(C0, Wo, bo, ATT0);
    ln_rows_k<<<32, 256, 0, stream>>>(ATT0, X0, ln1_g, ln1_b, Y1);
    ffn1_k<<<dim3(32, 4), 256, 0, stream>>>(Y1, W1, Hp1);
    ffn2_k<<<dim3(8, 16), 256, 0, stream>>>(Hp1, b1, W2, Hp2);
    ln2_k<<<32, 256, 0, stream>>>(Hp2, b2, Y1, ln2_g, ln2_b, X2);
    headp_k<<<dim3(32, 8), 256, 0, stream>>>(X2, Wh, bh, Wf, Pl);
    final_k<<<1, 64, 0, stream>>>(Pl, bf, out);
}

// Round 6
// 211.720 us; speedup vs baseline: 2.2243x; 1.1561x over previous
//
#include <hip/hip_runtime.h>
#include <hip/hip_bf16.h>

// ---------------------------------------------------------------------------
// PE table (1024x512 fp32) + zero gamma (fused)
// ---------------------------------------------------------------------------
__global__ __launch_bounds__(256) void pe_k(float* __restrict__ PE,
                                            float* __restrict__ gamma)
{
    int idx = blockIdx.x * 256 + threadIdx.x;      // < 524288
    int d = idx & 511, s = idx >> 9;
    float expo = (float)(d & ~1) * (1.0f / 512.0f);
    float ang = (float)s * exp2f(-expo * 13.287712379549449f); // 10000^-expo
    PE[idx] = (d & 1) ? cosf(ang) : sinf(ang);
    if (idx < 128) gamma[idx] = 0.f;
}

// ---------------------------------------------------------------------------
// qr_k: per (b,h): X0row = emb[tok[b,0]] + PE[0];
//   q0[f] = X0row . Wq[h][:,f] + bq[f];  alpha[b,h] = q0 . bk[h]
//   r[(b*4+h)][d] = sum_f q0[f] * Wk[h][d][f]
// Grid (32 b, 4 h).
// ---------------------------------------------------------------------------
__global__ __launch_bounds__(256) void qr_k(
    const int* __restrict__ inp, const float* __restrict__ emb,
    const float* __restrict__ PE, const float* __restrict__ Wp,
    const float* __restrict__ bp, float* __restrict__ X0,
    float* __restrict__ r, float* __restrict__ alpha)
{
    __shared__ float xs[512];
    __shared__ float red[256];
    __shared__ float q0s[128];
    int b = blockIdx.x, h = blockIdx.y, t = threadIdx.x;
    int tok0 = inp[b * 1024];
#pragma unroll
    for (int rep = 0; rep < 2; rep++) {
        int d = t + rep * 256;
        float v = emb[(long)tok0 * 512 + d] + PE[d];
        xs[d] = v;
        if (h == 0) X0[b * 512 + d] = v;
    }
    __syncthreads();

    int f = t & 127, dh = t >> 7;
    const float* wq = Wp + (long)h * 196608 + f;
    float acc = 0.f;
#pragma unroll 8
    for (int d = dh * 256; d < dh * 256 + 256; d++)
        acc += xs[d] * wq[(long)d * 384];
    red[t] = acc;
    __syncthreads();
    if (t < 128) q0s[t] = red[t] + red[t + 128] + bp[h * 384 + t];
    __syncthreads();
    if (t < 128) red[t] = q0s[t] * bp[h * 384 + 128 + t];
    __syncthreads();
    for (int w = 64; w >= 1; w >>= 1) {
        if (t < w) red[t] += red[t + w];
        __syncthreads();
    }
    if (t == 0) alpha[b * 4 + h] = red[0];

    const float4* q4 = (const float4*)q0s;
#pragma unroll
    for (int rep = 0; rep < 2; rep++) {
        int d = t + rep * 256;
        const float4* wr = (const float4*)(Wp + ((long)(h * 512 + d)) * 384 + 128);
        float a2 = 0.f;
#pragma unroll 8
        for (int f4 = 0; f4 < 32; f4++) {
            float4 w = wr[f4], qq = q4[f4];
            a2 += w.x * qq.x + w.y * qq.y + w.z * qq.z + w.w * qq.w;
        }
        r[((long)(b * 4 + h)) * 512 + d] = a2;
    }
}

// ---------------------------------------------------------------------------
// xu_k: fused u + t'-partials. Grid (32 b, 32 sc), 32 s per block.
//   Phase 1: stage x[s][d] = emb[tok]+PE[s] into LDS (row stride 516).
//   Phase 2: u[s,h] = x[s].r[b,h] + alpha;  gamma += sum u (atomic).
//   Phase 3: Tpp[(b*32+sc)][h][d] = sum_s x[s][d]*u[s,h].
// x gathered from global exactly once.
// ---------------------------------------------------------------------------
#define XP 516
__global__ __launch_bounds__(256) void xu_k(
    const int* __restrict__ inp, const float* __restrict__ emb,
    const float* __restrict__ PE, const float* __restrict__ r,
    const float* __restrict__ alpha, float* __restrict__ Tpp,
    float* __restrict__ gamma)
{
    __shared__ float xs[32 * XP];      // 66 KB
    __shared__ float rs[2048];         // r[b] 4x512
    __shared__ float us[128];          // u[s][h]
    __shared__ float red[256];
    __shared__ int  toks[32];
    int b = blockIdx.x, sc = blockIdx.y, t = threadIdx.x;
    int wave = t >> 6, lane = t & 63;

    if (t < 32) toks[t] = inp[b * 1024 + sc * 32 + t];
    // stage r[b] : 2048 floats
#pragma unroll
    for (int i = 0; i < 2; i++)
        ((float4*)rs)[t + i * 256] = ((const float4*)(r + (long)b * 2048))[t + i * 256];
    __syncthreads();

    // Phase 1: stage x rows (each wave: 8 rows; 1KB-coalesced emb/PE reads)
#pragma unroll
    for (int i = 0; i < 8; i++) {
        int row = wave * 8 + i;
        int tok = toks[row];
        const float4* e = (const float4*)&emb[(long)tok * 512 + lane * 8];
        const float4* pp = (const float4*)&PE[(long)(sc * 32 + row) * 512 + lane * 8];
        float4 e0 = e[0], e1 = e[1], p0 = pp[0], p1 = pp[1];
        float4 x0 = make_float4(e0.x + p0.x, e0.y + p0.y, e0.z + p0.z, e0.w + p0.w);
        float4 x1 = make_float4(e1.x + p1.x, e1.y + p1.y, e1.z + p1.z, e1.w + p1.w);
        *(float4*)&xs[row * XP + lane * 8] = x0;
        *(float4*)&xs[row * XP + lane * 8 + 4] = x1;
    }
    __syncthreads();

    // Phase 2: u[s,h] = x[s].r[h] + alpha[h]   (thread = (s,h,half))
    {
        int s = t >> 3, h = (t >> 1) & 3, half = t & 1;
        const float* xrow = xs + s * XP + half * 256;
        const float* rrow = rs + h * 512 + half * 256;
        float acc = 0.f;
#pragma unroll 8
        for (int k = 0; k < 64; k++) {
            float4 xv = *(const float4*)&xrow[k * 4];
            float4 rv = *(const float4*)&rrow[k * 4];
            acc += xv.x * rv.x + xv.y * rv.y + xv.z * rv.z + xv.w * rv.w;
        }
        acc += __shfl_xor(acc, 1);
        if (half == 0) us[s * 4 + h] = acc + alpha[b * 4 + h];
    }
    __syncthreads();

    // gamma partial: red[h*32+s] = us[s][h], tree-reduce over s, atomicAdd
    if (t < 128) {
        int s = t & 31, h = t >> 5;
        red[h * 32 + s] = us[s * 4 + h];
    }
    __syncthreads();
#pragma unroll
    for (int w = 16; w >= 1; w >>= 1) {
        if (t < 128 && (t & 31) < w) red[t] += red[t + w];
        __syncthreads();
    }
    if (t < 4) atomicAdd(&gamma[b * 4 + t], red[t * 32]);

    // Phase 3: t' partials
    float acc[4][2] = {};
#pragma unroll 4
    for (int s = 0; s < 32; s++) {
        float x0 = xs[s * XP + t];
        float x1 = xs[s * XP + 256 + t];
#pragma unroll
        for (int h = 0; h < 4; h++) {
            float uv = us[s * 4 + h];
            acc[h][0] += uv * x0;
            acc[h][1] += uv * x1;
        }
    }
    long base = (long)(b * 32 + sc) * 2048;
#pragma unroll
    for (int h = 0; h < 4; h++) {
        Tpp[base + h * 512 + t] = acc[h][0];
        Tpp[base + h * 512 + 256 + t] = acc[h][1];
    }
}

// ---------------------------------------------------------------------------
// att1_k: c0[b, h*128+e] = scale*(sum_d t'[h][d] Wv[h][d][e] + gamma[h] bv[h][e])
// Grid (32 b, 8 jt). Sums the 32 sc-partials of t' on load.
// ---------------------------------------------------------------------------
__global__ __launch_bounds__(256) void att1_k(
    const float* __restrict__ Tpp, const float* __restrict__ gamma,
    const float* __restrict__ Wp, const float* __restrict__ bp,
    float* __restrict__ C0)
{
    __shared__ float tps[512];
    __shared__ float red[256];
    int b = blockIdx.x, jt = blockIdx.y, t = threadIdx.x;
    int h = jt >> 1, e0 = (jt & 1) * 64;
#pragma unroll
    for (int i = 0; i < 2; i++) {
        int d = t + i * 256;
        float v = 0.f;
#pragma unroll 8
        for (int sc = 0; sc < 32; sc++)
            v += Tpp[(long)b * 65536 + sc * 2048 + h * 512 + d];
        tps[d] = v;
    }
    __syncthreads();
    int e = e0 + (t & 63), rg = t >> 6;
    const float* wv = Wp + (long)h * 196608 + 256 + e;
    float acc = 0.f;
#pragma unroll 8
    for (int d = rg * 128; d < rg * 128 + 128; d++)
        acc += tps[d] * wv[(long)d * 384];
    red[t] = acc;
    __syncthreads();
    if (t < 64) {
        float sum = red[t] + red[t + 64] + red[t + 128] + red[t + 192];
        float c = 0.03125f * (sum + gamma[b * 4 + h] * bp[h * 384 + 256 + e0 + t]);
        C0[b * 512 + h * 128 + e0 + t] = c;
    }
}

// ---------------------------------------------------------------------------
// att2_k: ATT0 = c0 @ Wo + bo.  Grid (32 b, 8 jt).
// ---------------------------------------------------------------------------
__global__ __launch_bounds__(256) void att2_k(
    const float* __restrict__ C0, const float* __restrict__ Wo,
    const float* __restrict__ bo, float* __restrict__ ATT0)
{
    __shared__ float c0s[512];
    __shared__ float red[256];
    int b = blockIdx.x, jt = blockIdx.y, t = threadIdx.x;
    c0s[t] = C0[b * 512 + t];
    c0s[t + 256] = C0[b * 512 + t + 256];
    __syncthreads();
    int j = jt * 64 + (t & 63), rg = t >> 6;
    float acc = 0.f;
#pragma unroll 8
    for (int d = rg * 128; d < rg * 128 + 128; d++)
        acc += c0s[d] * Wo[(long)d * 512 + j];
    red[t] = acc;
    __syncthreads();
    if (t < 64) {
        int jj = jt * 64 + t;
        ATT0[b * 512 + jj] = red[t] + red[t + 64] + red[t + 128] + red[t + 192] + bo[jj];
    }
}

// ---------------------------------------------------------------------------
// LN1: Y1 = LN(ATT0 + X0)*g + b.  Grid 32.
// ---------------------------------------------------------------------------
__global__ __launch_bounds__(256) void ln_rows_k(
    const float* __restrict__ in, const float* __restrict__ res,
    const float* __restrict__ g, const float* __restrict__ bta,
    float* __restrict__ out)
{
    int b = blockIdx.x;
    int t = threadIdx.x;
    float a0 = in[b * 512 + t] + res[b * 512 + t];
    float a1 = in[b * 512 + t + 256] + res[b * 512 + t + 256];

    __shared__ float sd[8];
    float s = a0 + a1;
#pragma unroll
    for (int off = 32; off; off >>= 1) s += __shfl_down(s, off);
    if ((t & 63) == 0) sd[t >> 6] = s;
    __syncthreads();
    float mean = (sd[0] + sd[1] + sd[2] + sd[3]) * (1.0f / 512.0f);

    float d0 = a0 - mean, d1 = a1 - mean;
    float v = d0 * d0 + d1 * d1;
#pragma unroll
    for (int off = 32; off; off >>= 1) v += __shfl_down(v, off);
    if ((t & 63) == 0) sd[4 + (t >> 6)] = v;
    __syncthreads();
    float var = (sd[4] + sd[5] + sd[6] + sd[7]) * (1.0f / 512.0f);
    float rstd = rsqrtf(var + 0.001f);

    out[b * 512 + t] = d0 * rstd * g[t] + bta[t];
    out[b * 512 + t + 256] = d1 * rstd * g[t + 256] + bta[t + 256];
}

// ---------------------------------------------------------------------------
// FFN1 partials: Hp1[ks][32][2048] = Y1[:, kchunk] @ W1[kchunk, :]
// Grid (32 jt, 4 ks).
// ---------------------------------------------------------------------------
__global__ __launch_bounds__(256) void ffn1_k(
    const float* __restrict__ Y1, const float* __restrict__ W1,
    float* __restrict__ Hp1)
{
    __shared__ float at[32][128];
    int jt = blockIdx.x, ks = blockIdx.y, t = threadIdx.x;
#pragma unroll
    for (int i = 0; i < 4; i++) {
        int idx = t + i * 256;
        int row = idx >> 5, f4 = idx & 31;
        ((float4*)at)[idx] = ((const float4*)(Y1 + (long)row * 512 + ks * 128))[f4];
    }
    __syncthreads();
    int j = jt * 64 + (t & 63), rg = t >> 6;
    float acc[8] = {};
    const float* wp = W1 + (long)(ks * 128) * 2048 + j;
#pragma unroll 4
    for (int k = 0; k < 128; k++) {
        float wv = wp[(long)k * 2048];
#pragma unroll
        for (int rr = 0; rr < 8; rr++)
            acc[rr] += at[rg * 8 + rr][k] * wv;
    }
#pragma unroll
    for (int rr = 0; rr < 8; rr++)
        Hp1[((long)(ks * 32 + rg * 8 + rr)) * 2048 + j] = acc[rr];
}

// ---------------------------------------------------------------------------
// FFN2 partials, fused H1 = relu(sum_ks Hp1 + b1) at staging.
// Hp2[ks][32][512] = H1[:, kchunk] @ W2[kchunk, :].  Grid (8 jt, 16 ks).
// ---------------------------------------------------------------------------
__global__ __launch_bounds__(256) void ffn2_k(
    const float* __restrict__ Hp1, const float* __restrict__ b1,
    const float* __restrict__ W2, float* __restrict__ Hp2)
{
    __shared__ float at[32][128];
    int jt = blockIdx.x, ks = blockIdx.y, t = threadIdx.x;
#pragma unroll
    for (int i = 0; i < 4; i++) {
        int idx = t + i * 256;
        int row = idx >> 5, f4 = idx & 31;
        int col4 = ks * 32 + f4;
        float4 v = ((const float4*)b1)[col4];
#pragma unroll
        for (int p = 0; p < 4; p++) {
            float4 pv = ((const float4*)Hp1)[(long)p * 16384 + (long)row * 512 + col4];
            v.x += pv.x; v.y += pv.y; v.z += pv.z; v.w += pv.w;
        }
        v.x = fmaxf(v.x, 0.f); v.y = fmaxf(v.y, 0.f);
        v.z = fmaxf(v.z, 0.f); v.w = fmaxf(v.w, 0.f);
        ((float4*)at)[idx] = v;
    }
    __syncthreads();
    int j = jt * 64 + (t & 63), rg = t >> 6;
    float acc[8] = {};
    const float* wp = W2 + (long)(ks * 128) * 512 + j;
#pragma unroll 4
    for (int k = 0; k < 128; k++) {
        float wv = wp[(long)k * 512];
#pragma unroll
        for (int rr = 0; rr < 8; rr++)
            acc[rr] += at[rg * 8 + rr][k] * wv;
    }
#pragma unroll
    for (int rr = 0; rr < 8; rr++)
        Hp2[((long)(ks * 32 + rg * 8 + rr)) * 512 + j] = acc[rr];
}

// ---------------------------------------------------------------------------
// headp2_k: fused LN2 + head partials.  Grid (32 b, 8 jt).
//   X2row = LN(sum_ks Hp2 + b2 + Y1) (redundant per jt, cheap, L2-hot)
//   Pl[b][jt] = sum_{j in tile} relu(X2row.Wh[:,j]+bh[j])*Wf[j]
// ---------------------------------------------------------------------------
__global__ __launch_bounds__(256) void headp2_k(
    const float* __restrict__ Hp2, const float* __restrict__ b2,
    const float* __restrict__ Y1, const float* __restrict__ g,
    const float* __restrict__ bta, const float* __restrict__ Wh,
    const float* __restrict__ bh, const float* __restrict__ Wf,
    float* __restrict__ Pl)
{
    __shared__ float xs[512];
    __shared__ float red[256];
    __shared__ float sd[8];
    int b = blockIdx.x, jt = blockIdx.y, t = threadIdx.x;
    float a[2];
#pragma unroll
    for (int rep = 0; rep < 2; rep++) {
        int j = t + rep * 256;
        float v = b2[j] + Y1[b * 512 + j];
#pragma unroll
        for (int ks = 0; ks < 16; ks++)
            v += Hp2[((long)(ks * 32 + b)) * 512 + j];
        a[rep] = v;
    }
    float s = a[0] + a[1];
#pragma unroll
    for (int off = 32; off; off >>= 1) s += __shfl_down(s, off);
    if ((t & 63) == 0) sd[t >> 6] = s;
    __syncthreads();
    float mean = (sd[0] + sd[1] + sd[2] + sd[3]) * (1.0f / 512.0f);
    float d0 = a[0] - mean, d1 = a[1] - mean;
    float v2 = d0 * d0 + d1 * d1;
#pragma unroll
    for (int off = 32; off; off >>= 1) v2 += __shfl_down(v2, off);
    if ((t & 63) == 0) sd[4 + (t >> 6)] = v2;
    __syncthreads();
    float var = (sd[4] + sd[5] + sd[6] + sd[7]) * (1.0f / 512.0f);
    float rstd = rsqrtf(var + 0.001f);
    xs[t] = d0 * rstd * g[t] + bta[t];
    xs[t + 256] = d1 * rstd * g[t + 256] + bta[t + 256];
    __syncthreads();

    int j = jt * 64 + (t & 63), rg = t >> 6;
    const float* w = Wh + j;
    float acc = 0.f;
#pragma unroll 8
    for (int d = rg * 128; d < rg * 128 + 128; d++)
        acc += xs[d] * w[(long)d * 512];
    red[t] = acc;
    __syncthreads();
    if (t < 64) {
        int jj = jt * 64 + t;
        float hid = red[t] + red[t + 64] + red[t + 128] + red[t + 192] + bh[jj];
        hid = fmaxf(hid, 0.f);
        float p = hid * Wf[jj];
#pragma unroll
        for (int off = 32; off; off >>= 1) p += __shfl_down(p, off);
        if (t == 0) Pl[b * 8 + jt] = p;
    }
}

__global__ __launch_bounds__(64) void final_k(
    const float* __restrict__ Pl, const float* __restrict__ bf,
    float* __restrict__ out)
{
    int t = threadIdx.x;
    if (t < 32) {
        float logit = bf[0];
#pragma unroll
        for (int jt = 0; jt < 8; jt++) logit += Pl[t * 8 + jt];
        out[t] = logit;
        out[32 + t] = 1.f / (1.f + expf(-logit));
    }
}

// ---------------------------------------------------------------------------
extern "C" void kernel_launch(void* const* d_in, const int* in_sizes, int n_in,
                              void* d_out, int out_size, void* d_ws, size_t ws_size,
                              hipStream_t stream)
{
    const int*   inputs = (const int*)  d_in[0];
    const float* emb    = (const float*)d_in[1];
    const float* Wp     = (const float*)d_in[2];
    const float* bp     = (const float*)d_in[3];
    const float* Wo     = (const float*)d_in[4];
    const float* bo     = (const float*)d_in[5];
    const float* ln1_g  = (const float*)d_in[6];
    const float* ln1_b  = (const float*)d_in[7];
    const float* W1     = (const float*)d_in[8];
    const float* b1     = (const float*)d_in[9];
    const float* W2     = (const float*)d_in[10];
    const float* b2     = (const float*)d_in[11];
    const float* ln2_g  = (const float*)d_in[12];
    const float* ln2_b  = (const float*)d_in[13];
    const float* Wh     = (const float*)d_in[14];
    const float* bh     = (const float*)d_in[15];
    const float* Wf     = (const float*)d_in[16];
    const float* bf     = (const float*)d_in[17];
    float* out = (float*)d_out;

    char* p = (char*)d_ws;
    float* PE    = (float*)p;  p += 2097152;    // (1024,512)
    float* X0    = (float*)p;  p += 65536;      // (32,512)
    float* r     = (float*)p;  p += 262144;     // (128,512)
    float* alpha = (float*)p;  p += 1024;       // (128) +pad
    float* gamma = (float*)p;  p += 1024;       // (128) [zeroed in pe_k]
    float* Tpp   = (float*)p;  p += 8388608;    // (32,32,4,512)
    float* C0    = (float*)p;  p += 65536;      // (32,512)
    float* ATT0  = (float*)p;  p += 65536;      // (32,512)
    float* Y1    = (float*)p;  p += 65536;      // (32,512)
    float* Hp1   = (float*)p;  p += 1048576;    // (4,32,2048)
    float* Hp2   = (float*)p;  p += 1048576;    // (16,32,512)
    float* Pl    = (float*)p;  p += 1024;       // (32,8)

    pe_k<<<2048, 256, 0, stream>>>(PE, gamma);
    qr_k<<<dim3(32, 4), 256, 0, stream>>>(inputs, emb, PE, Wp, bp, X0, r, alpha);
    xu_k<<<dim3(32, 32), 256, 0, stream>>>(inputs, emb, PE, r, alpha, Tpp, gamma);
    att1_k<<<dim3(32, 8), 256, 0, stream>>>(Tpp, gamma, Wp, bp, C0);
    att2_k<<<dim3(32, 8), 256, 0, stream>>>(C0, Wo, bo, ATT0);
    ln_rows_k<<<32, 256, 0, stream>>>(ATT0, X0, ln1_g, ln1_b, Y1);
    ffn1_k<<<dim3(32, 4), 256, 0, stream>>>(Y1, W1, Hp1);
    ffn2_k<<<dim3(8, 16), 256, 0, stream>>>(Hp1, b1, W2, Hp2);
    headp2_k<<<dim3(32, 8), 256, 0, stream>>>(Hp2, b2, Y1, ln2_g, ln2_b,
                                              Wh, bh, Wf, Pl);
    final_k<<<1, 64, 0, stream>>>(Pl, bf, out);
}